// Round 3
// baseline (1374.077 us; speedup 1.0000x reference)
//
#include <hip/hip_runtime.h>
#include <hip/hip_bf16.h>
#include <stdint.h>

// Problem constants (from reference)
#define N_NODES 100000
#define N_EDGES 1600000
#define NFEAT   256
#define NHID    128
#define NEG_SLOPE 0.2f

#define NB_B       3125       // buckets of 32 nodes: 100000/32 exact
#define SLAB       1024       // fixed slab per bucket (mean fill 512)
#define BIN_BLOCKS 512        // 2 blocks/CU; per-(block,bucket) run ~1 edge

typedef __attribute__((ext_vector_type(8))) short short8;   // 8 bf16 (4 VGPRs)
typedef __attribute__((ext_vector_type(4))) float f32x4;    // MFMA C/D frag

__device__ __forceinline__ int clamp_node(int v) {
    unsigned u = (unsigned)v;
    return (u < (unsigned)N_NODES) ? (int)u : 0;
}

// fp32 -> bf16 (RNE). Exact when the fp32 value is already bf16-rounded.
__device__ __forceinline__ unsigned short f2bf(float f) {
    unsigned u = __float_as_uint(f);
    return (unsigned short)((u + 0x7fffu + ((u >> 16) & 1u)) >> 16);
}
// packed pair -> v_cvt_pk_bf16_f32 (low = a, high = b)
__device__ __forceinline__ unsigned pkbf(float a, float b) {
    __hip_bfloat162 t = __float22bfloat162_rn(make_float2(a, b));
    return *reinterpret_cast<unsigned*>(&t);
}
__device__ __forceinline__ float bflo(unsigned p) { return __uint_as_float(p << 16); }
__device__ __forceinline__ float bfhi(unsigned p) { return __uint_as_float(p & 0xffff0000u); }

// ---------------------------------------------------------------------------
// K0: W [256,128] fp32 -> Wt [128,256] bf16 (n-major).
// ---------------------------------------------------------------------------
__global__ __launch_bounds__(256) void k_conv(
    const float* __restrict__ W, unsigned short* __restrict__ Wt)
{
    int id = blockIdx.x * 256 + threadIdx.x;  // n*256 + k
    int n = id >> 8, k = id & 255;
    Wt[id] = f2bf(W[k * NHID + n]);
}

// ---------------------------------------------------------------------------
// K1: h = x @ W via bf16 MFMA (fp32 accum) -> hb bf16, fused attention
// scalars. ROUND-1 VERSION RESTORED VERBATIM (BM=128, A+B both LDS-staged,
// software-pipelined): the round-2 BM=64 / B-from-global variant was the
// +12 us regressor (1-deep L2 prefetch not hidden by 8 MFMAs).
// ---------------------------------------------------------------------------
#define LDS_STRIDE 40
__global__ __launch_bounds__(256) void k_gemm_mfma(
    const float* __restrict__ x,            // [N, 256] fp32 (bf16-valued)
    const unsigned short* __restrict__ Wt,  // [128, 256] bf16, n-major
    const float* __restrict__ atts,         // [128]
    const float* __restrict__ attd,         // [128]
    unsigned short* __restrict__ hb,        // [N, 128] bf16
    float* __restrict__ asrc,
    float* __restrict__ adst)
{
    __shared__ unsigned short As[128 * LDS_STRIDE];
    __shared__ unsigned short Bs[128 * LDS_STRIDE];
    __shared__ float satt[128][2];

    const int tid  = threadIdx.x;
    const int wave = tid >> 6;
    const int lane = tid & 63;
    const int wm = wave >> 1, wn = wave & 1;
    const int lr = lane & 15, q = lane >> 4;
    const int blockM = blockIdx.x * 128;

    const int sr = tid >> 1;
    const int hh = tid & 1;

    if (tid < 128) { satt[tid][0] = 0.f; satt[tid][1] = 0.f; }

    f32x4 acc[4][4];
#pragma unroll
    for (int a = 0; a < 4; ++a)
#pragma unroll
        for (int b = 0; b < 4; ++b) acc[a][b] = 0.f;

    const int growA = min(blockM + sr, N_NODES - 1);
    const float* xrow = x + (size_t)growA * NFEAT + hh * 16;
    const unsigned short* wrow = Wt + sr * NFEAT + hh * 16;

    float4 va0, va1, va2, va3;
    uint4  vb0, vb1;
    {   // preload tile 0
        const float4* xp = (const float4*)xrow;
        va0 = xp[0]; va1 = xp[1]; va2 = xp[2]; va3 = xp[3];
        vb0 = *(const uint4*)(wrow);
        vb1 = *(const uint4*)(wrow + 8);
    }

    for (int kt = 0; kt < 8; ++kt) {
        __syncthreads();  // WAR: previous iter's frag reads done
        uint4 pa0 = make_uint4(pkbf(va0.x, va0.y), pkbf(va0.z, va0.w),
                               pkbf(va1.x, va1.y), pkbf(va1.z, va1.w));
        uint4 pa1 = make_uint4(pkbf(va2.x, va2.y), pkbf(va2.z, va2.w),
                               pkbf(va3.x, va3.y), pkbf(va3.z, va3.w));
        *(uint4*)&As[sr * LDS_STRIDE + hh * 16 + 0] = pa0;
        *(uint4*)&As[sr * LDS_STRIDE + hh * 16 + 8] = pa1;
        *(uint4*)&Bs[sr * LDS_STRIDE + hh * 16 + 0] = vb0;
        *(uint4*)&Bs[sr * LDS_STRIDE + hh * 16 + 8] = vb1;
        __syncthreads();  // RAW: writes visible

        if (kt < 7) {     // issue next tile's loads NOW (overlap MFMA)
            const float4* xp = (const float4*)(xrow + (kt + 1) * 32);
            va0 = xp[0]; va1 = xp[1]; va2 = xp[2]; va3 = xp[3];
            vb0 = *(const uint4*)(wrow + (kt + 1) * 32);
            vb1 = *(const uint4*)(wrow + (kt + 1) * 32 + 8);
        }

        short8 af[4], bfr[4];
#pragma unroll
        for (int mt = 0; mt < 4; ++mt)
            af[mt] = *(const short8*)&As[(wm * 64 + mt * 16 + lr) * LDS_STRIDE + q * 8];
#pragma unroll
        for (int nt = 0; nt < 4; ++nt)
            bfr[nt] = *(const short8*)&Bs[(wn * 64 + nt * 16 + lr) * LDS_STRIDE + q * 8];

#pragma unroll
        for (int mt = 0; mt < 4; ++mt)
#pragma unroll
            for (int nt = 0; nt < 4; ++nt)
                acc[mt][nt] = __builtin_amdgcn_mfma_f32_16x16x32_bf16(
                    af[mt], bfr[nt], acc[mt][nt], 0, 0, 0);
    }

    // ---- fused attention partials: per-row dot with atts/attd ----
    float attsv[4], attdv[4];
#pragma unroll
    for (int nt = 0; nt < 4; ++nt) {
        attsv[nt] = atts[wn * 64 + nt * 16 + lr];
        attdv[nt] = attd[wn * 64 + nt * 16 + lr];
    }
#pragma unroll
    for (int mt = 0; mt < 4; ++mt) {
#pragma unroll
        for (int reg = 0; reg < 4; ++reg) {
            float s = 0.f, d = 0.f;
#pragma unroll
            for (int nt = 0; nt < 4; ++nt) {
                float v = acc[mt][nt][reg];
                s += v * attsv[nt];
                d += v * attdv[nt];
            }
#pragma unroll
            for (int mask = 8; mask > 0; mask >>= 1) {
                s += __shfl_xor(s, mask);
                d += __shfl_xor(d, mask);
            }
            if (lr == 0) {
                int lrow = wm * 64 + mt * 16 + q * 4 + reg;
                atomicAdd(&satt[lrow][0], s);
                atomicAdd(&satt[lrow][1], d);
            }
        }
    }

    // ---- hb epilogue ----
#pragma unroll
    for (int mt = 0; mt < 4; ++mt) {
#pragma unroll
        for (int reg = 0; reg < 4; ++reg) {
            int grow = blockM + wm * 64 + mt * 16 + q * 4 + reg;
            if (grow < N_NODES) {
                unsigned short* hp = hb + (size_t)grow * NHID + wn * 64 + lr;
#pragma unroll
                for (int nt = 0; nt < 4; ++nt)
                    hp[nt * 16] = f2bf(acc[mt][nt][reg]);
            }
        }
    }

    __syncthreads();
    if (tid < 128) {
        int g = blockM + tid;
        if (g < N_NODES) {
            asrc[g] = satt[tid][0];
            adst[g] = satt[tid][1];
        }
    }
}

// ---------------------------------------------------------------------------
// K2: bin edges into fixed per-bucket slabs (bucket = dst>>5, slab = 1024).
// 512 blocks (2/CU). Per-block LDS histogram -> one global cursor bump per
// (block,bucket) -> LDS-cursor scatter. Payload = src | (dst&31)<<17.
// ---------------------------------------------------------------------------
__global__ __launch_bounds__(256) void k_bin(
    const int* __restrict__ ei, int* __restrict__ gcur,
    unsigned* __restrict__ staged)
{
    __shared__ int hist[NB_B];   // then reused as cursor (12.5 KB)
    __shared__ int base[NB_B];   // 12.5 KB
    const int t = threadIdx.x;
    const int per = (N_EDGES + BIN_BLOCKS - 1) / BIN_BLOCKS;  // 3125
    const int e0 = blockIdx.x * per;
    const int e1 = min(e0 + per, N_EDGES);

    for (int i = t; i < NB_B; i += 256) hist[i] = 0;
    __syncthreads();
    for (int e = e0 + t; e < e1; e += 256)
        atomicAdd(&hist[clamp_node(ei[N_EDGES + e]) >> 5], 1);
    __syncthreads();
    for (int i = t; i < NB_B; i += 256) {
        int c = hist[i];
        base[i] = c ? atomicAdd(&gcur[i], c) : 0;
        hist[i] = 0;  // becomes cursor
    }
    __syncthreads();
    for (int e = e0 + t; e < e1; e += 256) {
        int d = clamp_node(ei[N_EDGES + e]);
        int s = clamp_node(ei[e]);
        int b = d >> 5;
        int pos = base[b] + atomicAdd(&hist[b], 1);
        if (pos < SLAB)  // Poisson(512) vs 1024: overflow prob ~0
            staged[(size_t)b * SLAB + pos] = (unsigned)s | ((unsigned)(d & 31) << 17);
    }
}

// ---------------------------------------------------------------------------
// K3 v3: NO counting sort. The sort existed only to make per-node edges
// contiguous for register accumulation; instead accumulate into an LDS f32
// array acc[32][128] with fire-and-forget ds_add_f32 (unsafeAtomicAdd).
//   Phase A: thread-parallel ew compute, buf[j]={pk,ew} written COALESCED
//            at j (no hist/scan/scatter -> those bank conflicts gone),
//            ssum via LDS atomic.
//   Phase B: waves stream edges in arrival order (perfect balance, no
//            degree tails); gather hb[src]; 2x ds_add per lane (cols 2l,
//            2l+1 -> exactly 2-way bank aliasing = free).
//   Phase C: per-node self-loop + normalize + FC + log_softmax.
// FP reordering across atomics: ~1 ulp on ~16-term sums, inside tolerance.
// ---------------------------------------------------------------------------
__global__ __launch_bounds__(256) void k_sort_agg(
    const unsigned* __restrict__ staged, const int* __restrict__ gcur,
    const float* __restrict__ asrc, const float* __restrict__ adst,
    const unsigned short* __restrict__ hb,
    const float* __restrict__ bias, const float* __restrict__ fcw,
    const float* __restrict__ fcb, float* __restrict__ out)
{
    __shared__ float2 buf[SLAB];        // 8 KB {pk bits, ew}
    __shared__ float acc[32][128];      // 16 KB accumulator
    __shared__ float ssum[32];
    __shared__ float asrc_s[32], adst_s[32];

    const int b = blockIdx.x;
    const int t = threadIdx.x;
    const int eb = b * SLAB;
    const int n = min(gcur[b], SLAB);
    const int nodeStart = b * 32;       // 3125*32 == 100000: no boundary

    {   // zero acc: 4096 floats = 1024 float4, 4 per thread
        float4* a4 = (float4*)&acc[0][0];
#pragma unroll
        for (int u = 0; u < 4; ++u) a4[t + 256 * u] = make_float4(0.f, 0.f, 0.f, 0.f);
    }
    if (t < 32) {
        ssum[t] = 0.f;
        adst_s[t] = adst[nodeStart + t];
        asrc_s[t] = asrc[nodeStart + t];
    }
    __syncthreads();

    // ---- Phase A: ew compute, coalesced stage to LDS ----
    for (int j = t; j < n; j += 256) {
        unsigned pk = staged[eb + j];
        int s  = pk & 0x1FFFF;
        int dl = (pk >> 17) & 31;
        float a = asrc[s] + adst_s[dl];
        a = (a > 0.f) ? a : NEG_SLOPE * a;
        float ew = __expf(fminf(a, 60.f));
        unsafeAtomicAdd(&ssum[dl], ew);
        buf[j] = make_float2(__uint_as_float(pk), ew);
    }
    __syncthreads();

    const int wave = t >> 6;
    const int lane = t & 63;
    const unsigned* hrows = (const unsigned*)hb;

    // ---- Phase B: edge-parallel gather + LDS atomic accumulate ----
    const int chunk = (n + 3) >> 2;
    const int j0 = wave * chunk;
    const int j1 = min(j0 + chunk, n);
    int j = j0;
    for (; j + 8 <= j1; j += 8) {
        float2 m[8];
        unsigned p[8];
#pragma unroll
        for (int u = 0; u < 8; ++u) m[u] = buf[j + u];
#pragma unroll
        for (int u = 0; u < 8; ++u)
            p[u] = hrows[(size_t)(__float_as_uint(m[u].x) & 0x1FFFF) * 64u + lane];
#pragma unroll
        for (int u = 0; u < 8; ++u) {
            int dl = (__float_as_uint(m[u].x) >> 17) & 31;
            unsafeAtomicAdd(&acc[dl][2 * lane],     m[u].y * bflo(p[u]));
            unsafeAtomicAdd(&acc[dl][2 * lane + 1], m[u].y * bfhi(p[u]));
        }
    }
    for (; j < j1; ++j) {
        float2 m = buf[j];
        unsigned pk = __float_as_uint(m.x);
        unsigned p = hrows[(size_t)(pk & 0x1FFFF) * 64u + lane];
        int dl = (pk >> 17) & 31;
        unsafeAtomicAdd(&acc[dl][2 * lane],     m.y * bflo(p));
        unsafeAtomicAdd(&acc[dl][2 * lane + 1], m.y * bfhi(p));
    }
    __syncthreads();

    // ---- Phase C: per-node finalize + FC + log_softmax ----
    const float b0 = bias[2 * lane], b1 = bias[2 * lane + 1];
    const float w00 = fcw[2 * lane], w01 = fcw[2 * lane + 1];
    const float w10 = fcw[NHID + 2 * lane], w11 = fcw[NHID + 2 * lane + 1];
    const float fb0 = fcb[0], fb1 = fcb[1];

    for (int ln = wave * 8; ln < wave * 8 + 8; ++ln) {
        int i = nodeStart + ln;

        // self loop
        float e0 = asrc_s[ln] + adst_s[ln];
        e0 = (e0 > 0.f) ? e0 : NEG_SLOPE * e0;
        float w = __expf(fminf(e0, 60.f));
        unsigned pself = hrows[(unsigned)i * 64u + lane];
        float accx = acc[ln][2 * lane]     + w * bflo(pself);
        float accy = acc[ln][2 * lane + 1] + w * bfhi(pself);
        float ssv  = ssum[ln] + w;

        float inv = 1.0f / (ssv + 1e-16f);
        float ox = accx * inv + b0;
        float oy = accy * inv + b1;

        float l0 = ox * w00 + oy * w01;
        float l1 = ox * w10 + oy * w11;
#pragma unroll
        for (int off = 32; off > 0; off >>= 1) {
            l0 += __shfl_down(l0, off);
            l1 += __shfl_down(l1, off);
        }
        if (lane == 0) {
            l0 += fb0;
            l1 += fb1;
            float m = fmaxf(l0, l1);
            float ls = m + __logf(__expf(l0 - m) + __expf(l1 - m));
            ((float2*)out)[i] = make_float2(l0 - ls, l1 - ls);
        }
    }
}

// ---------------------------------------------------------------------------
extern "C" void kernel_launch(void* const* d_in, const int* in_sizes, int n_in,
                              void* d_out, int out_size, void* d_ws, size_t ws_size,
                              hipStream_t stream)
{
    const float* x    = (const float*)d_in[0];
    const int*   ei   = (const int*)d_in[1];
    const float* W    = (const float*)d_in[2];
    const float* atts = (const float*)d_in[3];
    const float* attd = (const float*)d_in[4];
    const float* bias = (const float*)d_in[5];
    const float* fcw  = (const float*)d_in[6];
    const float* fcb  = (const float*)d_in[7];
    float*       out  = (float*)d_out;

    char* base = (char*)d_ws;
    size_t off = 0;
    auto carve = [&](size_t bytes) -> char* {
        char* p = base + off;
        off = (off + bytes + 255) & ~(size_t)255;
        return p;
    };
    unsigned short* hb     = (unsigned short*)carve((size_t)N_NODES * NHID * 2); // 25.6 MB
    float*          asrc   = (float*)carve(N_NODES * 4);
    float*          adst   = (float*)carve(N_NODES * 4);
    int*            gcur   = (int*)carve(NB_B * 4);
    unsigned*       staged = (unsigned*)carve((size_t)NB_B * SLAB * 4);          // 12.8 MB
    unsigned short* Wt     = (unsigned short*)carve(NHID * NFEAT * 2);           // 64 KB
    (void)ws_size; (void)in_sizes; (void)n_in; (void)out_size;

    hipMemsetAsync(gcur, 0, NB_B * 4, stream);

    const int GB = (N_NODES + 127) / 128;  // 782

    k_conv<<<(NHID * NFEAT) / 256, 256, 0, stream>>>(W, Wt);
    k_gemm_mfma<<<GB, 256, 0, stream>>>(x, Wt, atts, attd, hb, asrc, adst);
    k_bin<<<BIN_BLOCKS, 256, 0, stream>>>(ei, gcur, staged);
    k_sort_agg<<<NB_B, 256, 0, stream>>>(staged, gcur, asrc, adst, hb,
                                         bias, fcw, fcb, out);
}

// Round 4
// 318.116 us; speedup vs baseline: 4.3194x; 4.3194x over previous
//
#include <hip/hip_runtime.h>
#include <hip/hip_bf16.h>
#include <stdint.h>

// Problem constants (from reference)
#define N_NODES 100000
#define N_EDGES 1600000
#define NFEAT   256
#define NHID    128
#define NEG_SLOPE 0.2f

#define NB_B       3125       // buckets of 32 nodes: 100000/32 exact
#define SLAB       1024       // fixed slab per bucket (mean fill 512)
#define BIN_BLOCKS 512        // 2 blocks/CU; per-(block,bucket) run ~1 edge

typedef __attribute__((ext_vector_type(8))) short short8;   // 8 bf16 (4 VGPRs)
typedef __attribute__((ext_vector_type(4))) float f32x4;    // MFMA C/D frag

__device__ __forceinline__ int clamp_node(int v) {
    unsigned u = (unsigned)v;
    return (u < (unsigned)N_NODES) ? (int)u : 0;
}

// fp32 -> bf16 (RNE). Exact when the fp32 value is already bf16-rounded.
__device__ __forceinline__ unsigned short f2bf(float f) {
    unsigned u = __float_as_uint(f);
    return (unsigned short)((u + 0x7fffu + ((u >> 16) & 1u)) >> 16);
}
// packed pair -> v_cvt_pk_bf16_f32 (low = a, high = b)
__device__ __forceinline__ unsigned pkbf(float a, float b) {
    __hip_bfloat162 t = __float22bfloat162_rn(make_float2(a, b));
    return *reinterpret_cast<unsigned*>(&t);
}
__device__ __forceinline__ float bflo(unsigned p) { return __uint_as_float(p << 16); }
__device__ __forceinline__ float bfhi(unsigned p) { return __uint_as_float(p & 0xffff0000u); }

// ---------------------------------------------------------------------------
// K0: W [256,128] fp32 -> Wt [128,256] bf16 (n-major).
// ---------------------------------------------------------------------------
__global__ __launch_bounds__(256) void k_conv(
    const float* __restrict__ W, unsigned short* __restrict__ Wt)
{
    int id = blockIdx.x * 256 + threadIdx.x;  // n*256 + k
    int n = id >> 8, k = id & 255;
    Wt[id] = f2bf(W[k * NHID + n]);
}

// ---------------------------------------------------------------------------
// K1: h = x @ W via bf16 MFMA (fp32 accum) -> hb bf16, fused attention
// scalars. v3: SAME proven LDS-staged + software-pipelined structure and
// BM=128 tile as round-1, but 1024 threads/block (16 waves, 16x64 wave
// tiles). Per-thread state: acc[4] (16 VGPR) + 1 A-frag + tiny staging ->
// fits the 64-VGPR / 8-waves-per-SIMD budget (__launch_bounds__(1024,8)),
// giving 2 blocks/CU = 32 waves/CU vs round-1's ~12 (37%). Round-1 gemm was
// latency-bound at low occupancy (1.9 TB/s on a 128 MB stream).
// ---------------------------------------------------------------------------
#define LDS_STRIDE 40
__global__ __launch_bounds__(1024, 8) void k_gemm_mfma(
    const float* __restrict__ x,            // [N, 256] fp32 (bf16-valued)
    const unsigned short* __restrict__ Wt,  // [128, 256] bf16, n-major
    const float* __restrict__ atts,         // [128]
    const float* __restrict__ attd,         // [128]
    unsigned short* __restrict__ hb,        // [N, 128] bf16
    float* __restrict__ asrc,
    float* __restrict__ adst)
{
    __shared__ unsigned short As[128 * LDS_STRIDE];
    __shared__ unsigned short Bs[128 * LDS_STRIDE];
    __shared__ float satt[128][2];

    const int tid  = threadIdx.x;
    const int wave = tid >> 6;                 // 0..15
    const int lane = tid & 63;
    const int wm = wave >> 1, wn = wave & 1;   // 8x2 wave grid; tile 16x64
    const int lr = lane & 15, q = lane >> 4;
    const int blockM = blockIdx.x * 128;

    const int sr = tid >> 3;   // staging row 0..127
    const int sq = tid & 7;    // 4-elem segment within 32-wide k-tile

    if (tid < 128) { satt[tid][0] = 0.f; satt[tid][1] = 0.f; }

    f32x4 acc[4];
#pragma unroll
    for (int b = 0; b < 4; ++b) acc[b] = 0.f;

    const int growA = min(blockM + sr, N_NODES - 1);
    const float* xrow = x + (size_t)growA * NFEAT + sq * 4;
    const unsigned short* wrow = Wt + sr * NFEAT + sq * 4;

    float4 va = *(const float4*)xrow;           // preload tile 0
    uint2  vb = *(const uint2*)wrow;

    for (int kt = 0; kt < 8; ++kt) {
        __syncthreads();  // WAR: previous iter's frag reads done
        uint2 pa = make_uint2(pkbf(va.x, va.y), pkbf(va.z, va.w));
        *(uint2*)&As[sr * LDS_STRIDE + sq * 4] = pa;
        *(uint2*)&Bs[sr * LDS_STRIDE + sq * 4] = vb;
        __syncthreads();  // RAW: writes visible

        if (kt < 7) {     // issue next tile's loads NOW (overlap MFMA)
            va = *(const float4*)(xrow + (kt + 1) * 32);
            vb = *(const uint2*)(wrow + (kt + 1) * 32);
        }

        short8 af = *(const short8*)&As[(wm * 16 + lr) * LDS_STRIDE + q * 8];
#pragma unroll
        for (int nt = 0; nt < 4; ++nt) {
            short8 bfr = *(const short8*)&Bs[(wn * 64 + nt * 16 + lr) * LDS_STRIDE + q * 8];
            acc[nt] = __builtin_amdgcn_mfma_f32_16x16x32_bf16(af, bfr, acc[nt], 0, 0, 0);
        }
    }

    // ---- fused attention partials: per-row dot with atts/attd ----
    float attsv[4], attdv[4];
#pragma unroll
    for (int nt = 0; nt < 4; ++nt) {
        attsv[nt] = atts[wn * 64 + nt * 16 + lr];
        attdv[nt] = attd[wn * 64 + nt * 16 + lr];
    }
#pragma unroll
    for (int reg = 0; reg < 4; ++reg) {
        float s = 0.f, d = 0.f;
#pragma unroll
        for (int nt = 0; nt < 4; ++nt) {
            float v = acc[nt][reg];
            s += v * attsv[nt];
            d += v * attdv[nt];
        }
#pragma unroll
        for (int mask = 8; mask > 0; mask >>= 1) {
            s += __shfl_xor(s, mask);
            d += __shfl_xor(d, mask);
        }
        if (lr == 0) {
            int lrow = wm * 16 + q * 4 + reg;
            atomicAdd(&satt[lrow][0], s);
            atomicAdd(&satt[lrow][1], d);
        }
    }

    // ---- hb epilogue ----
#pragma unroll
    for (int reg = 0; reg < 4; ++reg) {
        int grow = blockM + wm * 16 + q * 4 + reg;
        if (grow < N_NODES) {
            unsigned short* hp = hb + (size_t)grow * NHID + wn * 64 + lr;
#pragma unroll
            for (int nt = 0; nt < 4; ++nt)
                hp[nt * 16] = f2bf(acc[nt][reg]);
        }
    }

    __syncthreads();
    if (tid < 128) {
        int g = blockM + tid;
        if (g < N_NODES) {
            asrc[g] = satt[tid][0];
            adst[g] = satt[tid][1];
        }
    }
}

// ---------------------------------------------------------------------------
// K2: bin edges into fixed per-bucket slabs (bucket = dst>>5, slab = 1024).
// 512 blocks (2/CU). Per-block LDS histogram -> one global cursor bump per
// (block,bucket) -> LDS-cursor scatter. Payload = src | (dst&31)<<17.
// ---------------------------------------------------------------------------
__global__ __launch_bounds__(256) void k_bin(
    const int* __restrict__ ei, int* __restrict__ gcur,
    unsigned* __restrict__ staged)
{
    __shared__ int hist[NB_B];   // then reused as cursor (12.5 KB)
    __shared__ int base[NB_B];   // 12.5 KB
    const int t = threadIdx.x;
    const int per = (N_EDGES + BIN_BLOCKS - 1) / BIN_BLOCKS;  // 3125
    const int e0 = blockIdx.x * per;
    const int e1 = min(e0 + per, N_EDGES);

    for (int i = t; i < NB_B; i += 256) hist[i] = 0;
    __syncthreads();
    for (int e = e0 + t; e < e1; e += 256)
        atomicAdd(&hist[clamp_node(ei[N_EDGES + e]) >> 5], 1);
    __syncthreads();
    for (int i = t; i < NB_B; i += 256) {
        int c = hist[i];
        base[i] = c ? atomicAdd(&gcur[i], c) : 0;
        hist[i] = 0;  // becomes cursor
    }
    __syncthreads();
    for (int e = e0 + t; e < e1; e += 256) {
        int d = clamp_node(ei[N_EDGES + e]);
        int s = clamp_node(ei[e]);
        int b = d >> 5;
        int pos = base[b] + atomicAdd(&hist[b], 1);
        if (pos < SLAB)  // Poisson(512) vs 1024: overflow prob ~0
            staged[(size_t)b * SLAB + pos] = (unsigned)s | ((unsigned)(d & 31) << 17);
    }
}

// ---------------------------------------------------------------------------
// K3: per-bucket counting sort IN LDS, then per-node aggregation + fused FC
// + log_softmax. ROUND-2 VERSION RESTORED VERBATIM (proven 73.4 us): the
// round-3 LDS-float-atomic accumulate variant serialized (VALUBusy 3%,
// 15x slower) -- LDS float atomics are not a throughput primitive here.
// ---------------------------------------------------------------------------
__global__ __launch_bounds__(256) void k_sort_agg(
    const unsigned* __restrict__ staged, const int* __restrict__ gcur,
    const float* __restrict__ asrc, const float* __restrict__ adst,
    const unsigned short* __restrict__ hb,
    const float* __restrict__ bias, const float* __restrict__ fcw,
    const float* __restrict__ fcb, float* __restrict__ out)
{
    __shared__ float2 buf[SLAB];        // 8 KB sorted (src, ew)
    __shared__ int hist[32], scanv[32], cntv[32];
    __shared__ float asrc_s[32], adst_s[32];

    const int b = blockIdx.x;
    const int t = threadIdx.x;
    const int eb = b * SLAB;
    const int n = min(gcur[b], SLAB);
    const int nodeStart = b * 32;       // 3125*32 == 100000: no boundary

    if (t < 32) {
        hist[t] = 0;
        adst_s[t] = adst[nodeStart + t];
        asrc_s[t] = asrc[nodeStart + t];
    }
    __syncthreads();

    for (int j = t; j < n; j += 256)
        atomicAdd(&hist[(staged[eb + j] >> 17) & 31], 1);
    __syncthreads();

    if (t < 32) {  // parallel exclusive scan over 32 bins (lanes 0..31)
        int v = hist[t];
        int sc = v;
#pragma unroll
        for (int off = 1; off < 32; off <<= 1) {
            int u = __shfl_up(sc, off);
            if (t >= off) sc += u;
        }
        scanv[t] = sc - v;
        cntv[t] = v;
        hist[t] = 0;  // becomes cursor
    }
    __syncthreads();

    for (int j = t; j < n; j += 256) {
        unsigned pk = staged[eb + j];
        int s  = pk & 0x1FFFF;
        int dl = (pk >> 17) & 31;
        float a = asrc[s] + adst_s[dl];
        a = (a > 0.f) ? a : NEG_SLOPE * a;
        float ew = __expf(fminf(a, 60.f));
        int pos = scanv[dl] + atomicAdd(&hist[dl], 1);
        buf[pos] = make_float2(__int_as_float(s), ew);
    }
    __syncthreads();

    // ---- aggregation + fused FC + log_softmax ----
    const int wave = t >> 6;
    const int lane = t & 63;
    const unsigned* hrows = (const unsigned*)hb;

    // hoist per-lane FC constants out of the node loop
    const float b0 = bias[2 * lane], b1 = bias[2 * lane + 1];
    const float w00 = fcw[2 * lane], w01 = fcw[2 * lane + 1];
    const float w10 = fcw[NHID + 2 * lane], w11 = fcw[NHID + 2 * lane + 1];
    const float fb0 = fcb[0], fb1 = fcb[1];

    for (int ln = wave * 8; ln < wave * 8 + 8; ++ln) {
        int i = nodeStart + ln;

        // self loop
        float e0 = asrc_s[ln] + adst_s[ln];
        e0 = (e0 > 0.f) ? e0 : NEG_SLOPE * e0;
        float w = __expf(fminf(e0, 60.f));
        unsigned pself = hrows[(unsigned)i * 64u + lane];
        float accx = w * bflo(pself), accy = w * bfhi(pself), ssum = w;

        const int jb = scanv[ln];
        const int nn = cntv[ln];
        int j = 0;
        for (; j + 8 <= nn; j += 8) {
            float2 m[8];
            unsigned p[8];
#pragma unroll
            for (int u = 0; u < 8; ++u) m[u] = buf[jb + j + u];
#pragma unroll
            for (int u = 0; u < 8; ++u)
                p[u] = hrows[(unsigned)__float_as_int(m[u].x) * 64u + lane];
#pragma unroll
            for (int u = 0; u < 8; ++u) {
                accx += m[u].y * bflo(p[u]);
                accy += m[u].y * bfhi(p[u]);
                ssum += m[u].y;
            }
        }
        for (; j < nn; ++j) {
            float2 m = buf[jb + j];
            unsigned p = hrows[(unsigned)__float_as_int(m.x) * 64u + lane];
            accx += m.y * bflo(p);
            accy += m.y * bfhi(p);
            ssum += m.y;
        }

        float inv = 1.0f / (ssum + 1e-16f);
        float ox = accx * inv + b0;
        float oy = accy * inv + b1;

        float l0 = ox * w00 + oy * w01;
        float l1 = ox * w10 + oy * w11;
#pragma unroll
        for (int off = 32; off > 0; off >>= 1) {
            l0 += __shfl_down(l0, off);
            l1 += __shfl_down(l1, off);
        }
        if (lane == 0) {
            l0 += fb0;
            l1 += fb1;
            float m = fmaxf(l0, l1);
            float ls = m + __logf(__expf(l0 - m) + __expf(l1 - m));
            ((float2*)out)[i] = make_float2(l0 - ls, l1 - ls);
        }
    }
}

// ---------------------------------------------------------------------------
extern "C" void kernel_launch(void* const* d_in, const int* in_sizes, int n_in,
                              void* d_out, int out_size, void* d_ws, size_t ws_size,
                              hipStream_t stream)
{
    const float* x    = (const float*)d_in[0];
    const int*   ei   = (const int*)d_in[1];
    const float* W    = (const float*)d_in[2];
    const float* atts = (const float*)d_in[3];
    const float* attd = (const float*)d_in[4];
    const float* bias = (const float*)d_in[5];
    const float* fcw  = (const float*)d_in[6];
    const float* fcb  = (const float*)d_in[7];
    float*       out  = (float*)d_out;

    char* base = (char*)d_ws;
    size_t off = 0;
    auto carve = [&](size_t bytes) -> char* {
        char* p = base + off;
        off = (off + bytes + 255) & ~(size_t)255;
        return p;
    };
    unsigned short* hb     = (unsigned short*)carve((size_t)N_NODES * NHID * 2); // 25.6 MB
    float*          asrc   = (float*)carve(N_NODES * 4);
    float*          adst   = (float*)carve(N_NODES * 4);
    int*            gcur   = (int*)carve(NB_B * 4);
    unsigned*       staged = (unsigned*)carve((size_t)NB_B * SLAB * 4);          // 12.8 MB
    unsigned short* Wt     = (unsigned short*)carve(NHID * NFEAT * 2);           // 64 KB
    (void)ws_size; (void)in_sizes; (void)n_in; (void)out_size;

    hipMemsetAsync(gcur, 0, NB_B * 4, stream);

    const int GB = (N_NODES + 127) / 128;  // 782

    k_conv<<<(NHID * NFEAT) / 256, 256, 0, stream>>>(W, Wt);
    k_gemm_mfma<<<GB, 1024, 0, stream>>>(x, Wt, atts, attd, hb, asrc, adst);
    k_bin<<<BIN_BLOCKS, 256, 0, stream>>>(ei, gcur, staged);
    k_sort_agg<<<NB_B, 256, 0, stream>>>(staged, gcur, asrc, adst, hb,
                                         bias, fcw, fcb, out);
}